// Round 11
// baseline (878.366 us; speedup 1.0000x reference)
//
#include <hip/hip_runtime.h>
#include <math.h>

// LegacyVMambaBlock R11: single change vs R10 — conv_scan __launch_bounds__
// (1024, 1). Empirical model of this hipcc: 2nd arg = min BLOCKS/CU (CUDA
// semantics), default 2; VGPR cap = 512 / waves-per-SIMD. (1024)->32 waves->
// cap 64 (spilled); (1024,1)->16 waves->cap 128; scan needs ~70-110 -> no
// spill. Everything else proven R6-R10.

typedef __attribute__((ext_vector_type(8))) short bf16x8;
typedef __attribute__((ext_vector_type(4))) float f32x4;

#define T_TOKENS 65536
#define DMODEL 384
#define DINNER 768
#define DHIDDEN 1536

__device__ __forceinline__ float bf2f(unsigned short u) {
  unsigned int x = ((unsigned int)u) << 16;
  return __builtin_bit_cast(float, x);
}
__device__ __forceinline__ unsigned short f2bf(float f) {
  unsigned int x = __builtin_bit_cast(unsigned int, f);
  x += 0x7fffu + ((x >> 16) & 1u);
  return (unsigned short)(x >> 16);
}
__device__ __forceinline__ void unpack2(unsigned int u, float& lo, float& hi) {
  lo = __builtin_bit_cast(float, u << 16);
  hi = __builtin_bit_cast(float, u & 0xffff0000u);
}
__device__ __forceinline__ unsigned int pack2(float lo, float hi) {
  return (unsigned int)f2bf(lo) | ((unsigned int)f2bf(hi) << 16);
}

__device__ __forceinline__ void gload16(const void* g, void* l) {
  __builtin_amdgcn_global_load_lds(
      (const __attribute__((address_space(1))) void*)g,
      (__attribute__((address_space(3))) void*)l, 16, 0, 0);
}

// ---------- fused LN over f32 [T,384] -> bf16 token-major ----------
__global__ __launch_bounds__(256) void ln_fused_f32_384(
    const float* __restrict__ in, const float* __restrict__ g,
    const float* __restrict__ b, unsigned short* __restrict__ out) {
  const int tok = blockIdx.x * 4 + (threadIdx.x >> 6);
  const int lane = threadIdx.x & 63;
  const float2* row = (const float2*)(in + (size_t)tok * 384);
  float2 v[3];
  float s = 0.f, ss = 0.f;
#pragma unroll
  for (int k = 0; k < 3; k++) {
    v[k] = row[lane + 64 * k];
    s += v[k].x + v[k].y;
    ss += v[k].x * v[k].x + v[k].y * v[k].y;
  }
#pragma unroll
  for (int off = 32; off > 0; off >>= 1) {
    s += __shfl_xor(s, off);
    ss += __shfl_xor(ss, off);
  }
  const float m = s * (1.0f / 384.0f);
  const float r = rsqrtf(ss * (1.0f / 384.0f) - m * m + 1e-5f);
  unsigned int* op = (unsigned int*)(out + (size_t)tok * 384);
#pragma unroll
  for (int k = 0; k < 3; k++) {
    const int c = lane + 64 * k;
    const float2 gg = ((const float2*)g)[c];
    const float2 bb = ((const float2*)b)[c];
    op[c] = pack2((v[k].x - m) * r * gg.x + bb.x, (v[k].y - m) * r * gg.y + bb.y);
  }
}

// ---------- LN over bundle bf16 [cg][b][pos][8ch] -> token-major ----------
__global__ __launch_bounds__(256) void ln_bundle_768(
    const uint4* __restrict__ mixed, const float* __restrict__ g,
    const float* __restrict__ b, uint4* __restrict__ out) {
  const int tid = threadIdx.x;
  const int tk = tid >> 2, j = tid & 3;
  const int token = blockIdx.x * 64 + tk;
  const int bb_ = token >> 12, posb = token & 4095;
  const size_t slab = (size_t)bb_ * 4096 + posb;
  float s = 0.f, ss = 0.f;
#pragma unroll 1
  for (int cg = j; cg < 96; cg += 4) {
    const uint4 v = mixed[((size_t)cg * 16) * 4096 + slab];
    float e0, e1, e2, e3, e4, e5, e6, e7;
    unpack2(v.x, e0, e1); unpack2(v.y, e2, e3);
    unpack2(v.z, e4, e5); unpack2(v.w, e6, e7);
    s += (e0 + e1) + (e2 + e3) + (e4 + e5) + (e6 + e7);
    ss += e0 * e0 + e1 * e1 + e2 * e2 + e3 * e3 + e4 * e4 + e5 * e5 +
          e6 * e6 + e7 * e7;
  }
  s += __shfl_xor(s, 1); ss += __shfl_xor(ss, 1);
  s += __shfl_xor(s, 2); ss += __shfl_xor(ss, 2);
  const float m = s * (1.0f / 768.0f);
  const float r = rsqrtf(ss * (1.0f / 768.0f) - m * m + 1e-5f);
  const size_t tokbase = (size_t)token * 96;
#pragma unroll 1
  for (int cg = j; cg < 96; cg += 4) {
    const uint4 v = mixed[((size_t)cg * 16) * 4096 + slab];
    const float4 g0 = *(const float4*)(g + cg * 8);
    const float4 g1 = *(const float4*)(g + cg * 8 + 4);
    const float4 b0 = *(const float4*)(b + cg * 8);
    const float4 b1 = *(const float4*)(b + cg * 8 + 4);
    float e0, e1, e2, e3, e4, e5, e6, e7;
    unpack2(v.x, e0, e1); unpack2(v.y, e2, e3);
    unpack2(v.z, e4, e5); unpack2(v.w, e6, e7);
    uint4 o;
    o.x = pack2((e0 - m) * r * g0.x + b0.x, (e1 - m) * r * g0.y + b0.y);
    o.y = pack2((e2 - m) * r * g0.z + b0.z, (e3 - m) * r * g0.w + b0.w);
    o.z = pack2((e4 - m) * r * g1.x + b1.x, (e5 - m) * r * g1.y + b1.y);
    o.w = pack2((e6 - m) * r * g1.z + b1.z, (e7 - m) * r * g1.w + b1.w);
    out[tokbase + cg] = o;
  }
}

// ---------- weight prep: f32 [K,N] -> bf16 [N,K] ----------
__global__ __launch_bounds__(256) void wprep_kernel(const float* __restrict__ in,
                                                    unsigned short* __restrict__ out,
                                                    int K, int N) {
  __shared__ float t[32][33];
  const int k0 = blockIdx.x * 32, n0 = blockIdx.y * 32;
  const int a = threadIdx.x & 31, b8 = threadIdx.x >> 5;
#pragma unroll
  for (int i = 0; i < 4; i++)
    t[b8 + 8 * i][a] = in[(size_t)(k0 + b8 + 8 * i) * N + n0 + a];
  __syncthreads();
#pragma unroll
  for (int i = 0; i < 4; i++)
    out[(size_t)(n0 + b8 + 8 * i) * K + k0 + a] = f2bf(t[a][b8 + 8 * i]);
}

// ---------- GEMM 2-phase dbuf; EPI: 1=f32+res, 2=gelu bf16, 3=bundle bf16 ---
template <int EPI>
__global__ __launch_bounds__(256) void gemm_bt_kernel(
    const unsigned short* __restrict__ A, int lda,
    const unsigned short* __restrict__ Bt, int ldb, int KT,
    const float* __restrict__ bias, const float* __restrict__ res,
    void* __restrict__ C, int ldc, int nby) {
  __shared__ unsigned short smem[32768];  // 64KB: As 2x16KB | Bs 2x16KB
  char* const smc = (char*)smem;

  const int tid = threadIdx.x;
  const int w = tid >> 6, lane = tid & 63;
  const int cpx = gridDim.x >> 3;
  const int g = blockIdx.x;
  const int sw = (g & 7) * cpx + (g >> 3);
  const int bx = sw / nby, by = sw - bx * nby;
  const int tok0 = bx << 7, n0 = by << 7;

  const int wm = w >> 1, wn = w & 1;
  const int lrow = lane & 15, kgrp = lane >> 4;
  const int cx = lrow & 7;

  const int lr8 = lane >> 3;
  const int kce = ((lane & 7) ^ lr8) << 3;
  const unsigned short* Abase = A + (size_t)(tok0 + w * 32 + lr8) * lda + kce;
  const unsigned short* Bbase = Bt + (size_t)(n0 + w * 32 + lr8) * ldb + kce;

  f32x4 acc[4][4];
#pragma unroll
  for (int i = 0; i < 4; i++)
#pragma unroll
    for (int j = 0; j < 4; j++) {
      f32x4 z = {0.f, 0.f, 0.f, 0.f};
      acc[i][j] = z;
    }

  const int nt = KT >> 6;
#pragma unroll
  for (int i = 0; i < 4; i++) {
    gload16(Abase + (size_t)i * 8 * lda, smc + (w * 4 + i) * 1024);
    gload16(Bbase + (size_t)i * 8 * ldb, smc + 32768 + (w * 4 + i) * 1024);
  }
  __syncthreads();

  int buf = 0;
  for (int t = 0; t < nt; t++) {
    if (t + 1 < nt) {
      const int kt = (t + 1) << 6;
      const int bo = (buf ^ 1) * 16384;
#pragma unroll
      for (int i = 0; i < 4; i++) {
        gload16(Abase + (size_t)i * 8 * lda + kt, smc + bo + (w * 4 + i) * 1024);
        gload16(Bbase + (size_t)i * 8 * ldb + kt,
                smc + 32768 + bo + (w * 4 + i) * 1024);
      }
    }
    bf16x8 af[2][4], bf_[2][4];
    const int bo = buf * 16384;
#pragma unroll
    for (int ks = 0; ks < 2; ks++) {
#pragma unroll
      for (int f = 0; f < 4; f++) {
        const int co = ((ks * 4 + kgrp) ^ cx) << 4;
        af[ks][f] =
            *(const bf16x8*)(smc + bo + (wm * 64 + f * 16 + lrow) * 128 + co);
        bf_[ks][f] = *(const bf16x8*)(smc + 32768 + bo +
                                      (wn * 64 + f * 16 + lrow) * 128 + co);
      }
    }
#pragma unroll
    for (int ks = 0; ks < 2; ks++)
#pragma unroll
      for (int mf = 0; mf < 4; mf++)
#pragma unroll
        for (int nf = 0; nf < 4; nf++)
          acc[mf][nf] = __builtin_amdgcn_mfma_f32_16x16x32_bf16(
              af[ks][mf], bf_[ks][nf], acc[mf][nf], 0, 0, 0);
    __syncthreads();
    buf ^= 1;
  }

  if constexpr (EPI == 3) {
#pragma unroll
    for (int mf = 0; mf < 4; mf++)
#pragma unroll
      for (int nf = 0; nf < 4; nf++) {
        const int cl = wn * 64 + nf * 16 + lrow;
        const float bv = bias[n0 + cl];
#pragma unroll
        for (int r = 0; r < 4; r++) {
          const int tl = wm * 64 + mf * 16 + kgrp * 4 + r;
          smem[(cl >> 3) * 1032 + tl * 8 + (cl & 7)] =
              f2bf(acc[mf][nf][r] + bv);
        }
      }
    __syncthreads();
    const int bb_ = tok0 >> 12, pos0 = tok0 & 4095, cg0 = n0 >> 3;
    uint4* Cb = (uint4*)C;
#pragma unroll
    for (int e = 0; e < 8; e++) {
      const int lin = e * 256 + tid;
      const int cgl = lin >> 7, pp = lin & 127;
      const uint4 v = *(const uint4*)&smem[cgl * 1032 + pp * 8];
      Cb[((size_t)(cg0 + cgl) * 16 + bb_) * 4096 + pos0 + pp] = v;
    }
  } else {
#pragma unroll
    for (int mf = 0; mf < 4; mf++) {
#pragma unroll
      for (int nf = 0; nf < 4; nf++) {
        const int gcol = n0 + wn * 64 + nf * 16 + lrow;
        const float bv = bias ? bias[gcol] : 0.0f;
#pragma unroll
        for (int r = 0; r < 4; r++) {
          const int grow = tok0 + wm * 64 + mf * 16 + kgrp * 4 + r;
          float v = acc[mf][nf][r] + bv;
          const size_t idx = (size_t)grow * ldc + gcol;
          if constexpr (EPI == 1) {
            ((float*)C)[idx] = v + res[idx];
          } else {
            const float z = 1.5957691216057308f * (v + 0.044715f * v * v * v);
            const float gl = v / (1.0f + __expf(-z));
            ((unsigned short*)C)[idx] = f2bf(gl);
          }
        }
      }
    }
  }
}

// ---------- segmented bidirectional EMA over a register-held segment -------
__device__ __forceinline__ void ema_seg_reg(const unsigned int vals[16],
                                            const int seg,
                                            unsigned int res[16]) {
  const float A16 = 2.8211099e-4f;   // 0.6^16
  const float A32 = 7.9586611e-8f;   // 0.6^32
  float a, bv, t;
  float za = 0.f, zb = 0.f;
#pragma unroll
  for (int j = 0; j < 16; j++) {
    unpack2(vals[j], a, bv);
    za = 0.6f * za + 0.4f * a;
    zb = 0.6f * zb + 0.4f * bv;
  }
  t = __shfl_up(za, 1); if (seg >= 1) za += A16 * t;
  t = __shfl_up(zb, 1); if (seg >= 1) zb += A16 * t;
  t = __shfl_up(za, 2); if (seg >= 2) za += A32 * t;
  t = __shfl_up(zb, 2); if (seg >= 2) zb += A32 * t;
  float yfa = __shfl_up(za, 1), yfb = __shfl_up(zb, 1);
  if (seg == 0) { yfa = 0.f; yfb = 0.f; }
  float ua = 0.f, ub = 0.f;
#pragma unroll
  for (int j = 15; j >= 0; j--) {
    unpack2(vals[j], a, bv);
    ua = 0.6f * ua + 0.4f * a;
    ub = 0.6f * ub + 0.4f * bv;
  }
  t = __shfl_down(ua, 1); if (seg <= 2) ua += A16 * t;
  t = __shfl_down(ub, 1); if (seg <= 2) ub += A16 * t;
  t = __shfl_down(ua, 2); if (seg <= 1) ua += A32 * t;
  t = __shfl_down(ub, 2); if (seg <= 1) ub += A32 * t;
  float zba = __shfl_down(ua, 1), zbb = __shfl_down(ub, 1);
  if (seg == 3) { zba = 0.f; zbb = 0.f; }
  float fa = yfa, fb = yfb;
#pragma unroll
  for (int j = 0; j < 16; j++) {
    unpack2(vals[j], a, bv);
    fa = 0.6f * fa + 0.4f * a;
    fb = 0.6f * fb + 0.4f * bv;
    res[j] = pack2(fa, fb);
  }
  float ga = zba, gb = zbb;
#pragma unroll
  for (int j = 15; j >= 0; j--) {
    unpack2(vals[j], a, bv);
    ga = 0.6f * ga + 0.4f * a;
    gb = 0.6f * gb + 0.4f * bv;
    float ffa, ffb;
    unpack2(res[j], ffa, ffb);
    res[j] = pack2(0.25f * (ffa + ga), 0.25f * (ffb + gb));
  }
}

// ---------- fused dwconv3x3 + 4 EMA scans on bundle layout ----------
// 1024 threads, launch_bounds(1024, 1): 1 block/CU floor -> VGPR cap 128
// (needs ~70-110) -> NO spill. Thread = (cp, line, seg).
__global__ __launch_bounds__(1024, 1) void conv_scan_kernel(
    const uint4* __restrict__ p, const float* __restrict__ kconv,
    uint4* __restrict__ mixed) {
  __shared__ unsigned int loc[4][64][65];  // 66.56 KB
  __shared__ float klds[72];
  const int tid = threadIdx.x;
  const int cg = blockIdx.x;  // 0..95
  const int b = blockIdx.y;   // 0..15
  const uint4* pb = p + ((size_t)cg * 16 + b) * 4096;

  if (tid < 72) klds[tid] = kconv[(tid >> 3) * DINNER + cg * 8 + (tid & 7)];
  __syncthreads();

#pragma unroll 1
  for (int i = 0; i < 4; i++) {
    const int pos = tid + 1024 * i;
    const int h = pos >> 6, w = pos & 63;
    float acc[8];
#pragma unroll
    for (int j = 0; j < 8; j++) acc[j] = 0.f;
#pragma unroll
    for (int dh = 0; dh < 3; dh++) {
      const int hh = h + dh - 1;
      const bool vh = (unsigned)hh < 64u;
      const int hcl = min(max(hh, 0), 63);
#pragma unroll
      for (int dw = 0; dw < 3; dw++) {
        const int ww = w + dw - 1;
        const bool vv = vh && ((unsigned)ww < 64u);
        const int wcl = min(max(ww, 0), 63);
        uint4 pv = pb[hcl * 64 + wcl];
        if (!vv) { pv.x = 0; pv.y = 0; pv.z = 0; pv.w = 0; }
        const int t = dh * 3 + dw;
        float lo, hi;
        unpack2(pv.x, lo, hi);
        acc[0] += lo * klds[t * 8 + 0]; acc[1] += hi * klds[t * 8 + 1];
        unpack2(pv.y, lo, hi);
        acc[2] += lo * klds[t * 8 + 2]; acc[3] += hi * klds[t * 8 + 3];
        unpack2(pv.z, lo, hi);
        acc[4] += lo * klds[t * 8 + 4]; acc[5] += hi * klds[t * 8 + 5];
        unpack2(pv.w, lo, hi);
        acc[6] += lo * klds[t * 8 + 6]; acc[7] += hi * klds[t * 8 + 7];
      }
    }
    loc[0][h][w] = pack2(acc[0], acc[1]);
    loc[1][h][w] = pack2(acc[2], acc[3]);
    loc[2][h][w] = pack2(acc[4], acc[5]);
    loc[3][h][w] = pack2(acc[6], acc[7]);
  }
  __syncthreads();

  const int seg = tid & 3;          // segment within line
  const int ax = (tid >> 2) & 63;   // line index (col for H, row for W)
  const int cp = tid >> 8;          // channel-pair plane 0..3
  const int j0 = seg * 16;

  // H phase: columns (read-only); contribution held in regs
  unsigned int hcon[16];
  {
    unsigned int vals[16];
#pragma unroll
    for (int j = 0; j < 16; j++) vals[j] = loc[cp][j0 + j][ax];
    ema_seg_reg(vals, seg, hcon);
  }
  __syncthreads();

  // W phase: rows; own-segment read + write (out = v + 0.25*(lr+rl))
  {
    unsigned int vals[16], wcon[16];
#pragma unroll
    for (int j = 0; j < 16; j++) vals[j] = loc[cp][ax][j0 + j];
    ema_seg_reg(vals, seg, wcon);
#pragma unroll
    for (int j = 0; j < 16; j++) {
      float a, bv, ra, rb;
      unpack2(vals[j], a, bv);
      unpack2(wcon[j], ra, rb);
      loc[cp][ax][j0 + j] = pack2(a + ra, bv + rb);
    }
  }
  __syncthreads();

  // ADD phase: += 0.25*(tb+bt) down own column-segment
#pragma unroll
  for (int j = 0; j < 16; j++) {
    float a, bv, ra, rb;
    unpack2(loc[cp][j0 + j][ax], a, bv);
    unpack2(hcon[j], ra, rb);
    loc[cp][j0 + j][ax] = pack2(a + ra, bv + rb);
  }
  __syncthreads();

  uint4* mb = mixed + ((size_t)cg * 16 + b) * 4096;
#pragma unroll 1
  for (int i = 0; i < 4; i++) {
    const int pos = tid + 1024 * i;
    const int h = pos >> 6, w = pos & 63;
    uint4 st;
    st.x = loc[0][h][w];
    st.y = loc[1][h][w];
    st.z = loc[2][h][w];
    st.w = loc[3][h][w];
    mb[pos] = st;
  }
}

extern "C" void kernel_launch(void* const* d_in, const int* in_sizes, int n_in,
                              void* d_out, int out_size, void* d_ws,
                              size_t ws_size, hipStream_t stream) {
  const float* x = (const float*)d_in[0];
  const float* n1_g = (const float*)d_in[1];
  const float* n1_b = (const float*)d_in[2];
  const float* w_in = (const float*)d_in[3];
  const float* b_in = (const float*)d_in[4];
  const float* k_conv = (const float*)d_in[5];
  const float* on_g = (const float*)d_in[6];
  const float* on_b = (const float*)d_in[7];
  const float* w_out = (const float*)d_in[8];
  const float* b_out = (const float*)d_in[9];
  const float* n2_g = (const float*)d_in[10];
  const float* n2_b = (const float*)d_in[11];
  const float* w1 = (const float*)d_in[12];
  const float* b1 = (const float*)d_in[13];
  const float* w2 = (const float*)d_in[14];
  const float* b2 = (const float*)d_in[15];

  const size_t MB = 1024 * 1024;
  char* ws = (char*)d_ws;
  unsigned short* R1 = (unsigned short*)(ws + 3 * MB / 2);
  unsigned short* R2 = (unsigned short*)(ws + 3 * MB / 2 + 96 * MB);

  unsigned short* A1 = R2;                         // 48MB token-major
  unsigned short* wTin = R2 + (48 * MB) / 2;       // [768][384]
  unsigned short* p = R1;                          // 96MB BUNDLE; in-place
  unsigned short* A2 = R2;                         // 96MB token-major
  unsigned short* wTout = R1;                      // [384][768] (p dead)
  unsigned short* A3 = R1;                         // 48MB
  unsigned short* wT1 = R1 + (48 * MB) / 2;        // [1536][384]
  unsigned short* wT2 = wT1 + (size_t)1536 * 384;  // [384][1536]
  unsigned short* gb = R2;                         // 96MB token-major

  float* out = (float*)d_out;
  dim3 b256(256);

  // LN1(x) -> A1
  ln_fused_f32_384<<<T_TOKENS / 4, b256, 0, stream>>>(x, n1_g, n1_b, A1);
  wprep_kernel<<<dim3(12, 24), b256, 0, stream>>>(w_in, wTin, DMODEL, DINNER);
  // p(bundle) = A1 @ w_in + b_in
  gemm_bt_kernel<3><<<3072, b256, 0, stream>>>(A1, DMODEL, wTin, DMODEL, DMODEL,
                                               b_in, nullptr, p, DINNER, 6);
  // mixed(bundle) = conv+scan(p), in place
  conv_scan_kernel<<<dim3(96, 16), dim3(1024), 0, stream>>>(
      (const uint4*)p, k_conv, (uint4*)p);
  // LN(on)(mixed bundle) -> A2 token-major
  ln_bundle_768<<<1024, b256, 0, stream>>>((const uint4*)p, on_g, on_b,
                                           (uint4*)A2);
  wprep_kernel<<<dim3(24, 12), b256, 0, stream>>>(w_out, wTout, DINNER, DMODEL);
  // out = x + A2 @ w_out + b_out
  gemm_bt_kernel<1><<<1536, b256, 0, stream>>>(A2, DINNER, wTout, DINNER, DINNER,
                                               b_out, x, out, DMODEL, 3);
  // LN2(out) -> A3
  ln_fused_f32_384<<<T_TOKENS / 4, b256, 0, stream>>>(out, n2_g, n2_b, A3);
  wprep_kernel<<<dim3(12, 48), b256, 0, stream>>>(w1, wT1, DMODEL, DHIDDEN);
  wprep_kernel<<<dim3(48, 12), b256, 0, stream>>>(w2, wT2, DHIDDEN, DMODEL);
  // MLP split by tokens
  for (int hh = 0; hh < 2; hh++) {
    const size_t toff = (size_t)hh * 32768;
    gemm_bt_kernel<2><<<3072, b256, 0, stream>>>(
        A3 + toff * DMODEL, DMODEL, wT1, DMODEL, DMODEL, b1, nullptr, gb,
        DHIDDEN, 12);
    gemm_bt_kernel<1><<<768, b256, 0, stream>>>(
        gb, DHIDDEN, wT2, DHIDDEN, DHIDDEN, b2, out + toff * DMODEL,
        out + toff * DMODEL, DMODEL, 3);
  }
}

// Round 12
// 664.543 us; speedup vs baseline: 1.3218x; 1.3218x over previous
//
#include <hip/hip_runtime.h>
#include <math.h>

// LegacyVMambaBlock R12: conv_scan at 512 threads (the ONLY config empirically
// giving a 128-VGPR cap on this toolchain: R8). Each thread owns 2 channel
// planes; segmented EMA (16-elem regs + shfl carry) => ~90 live VGPR, no
// spill. 1024-thread blocks are compiler-pinned to 64 VGPR (R10/R11) - dead
// end. Everything else proven R6-R11.

typedef __attribute__((ext_vector_type(8))) short bf16x8;
typedef __attribute__((ext_vector_type(4))) float f32x4;

#define T_TOKENS 65536
#define DMODEL 384
#define DINNER 768
#define DHIDDEN 1536

__device__ __forceinline__ float bf2f(unsigned short u) {
  unsigned int x = ((unsigned int)u) << 16;
  return __builtin_bit_cast(float, x);
}
__device__ __forceinline__ unsigned short f2bf(float f) {
  unsigned int x = __builtin_bit_cast(unsigned int, f);
  x += 0x7fffu + ((x >> 16) & 1u);
  return (unsigned short)(x >> 16);
}
__device__ __forceinline__ void unpack2(unsigned int u, float& lo, float& hi) {
  lo = __builtin_bit_cast(float, u << 16);
  hi = __builtin_bit_cast(float, u & 0xffff0000u);
}
__device__ __forceinline__ unsigned int pack2(float lo, float hi) {
  return (unsigned int)f2bf(lo) | ((unsigned int)f2bf(hi) << 16);
}

__device__ __forceinline__ void gload16(const void* g, void* l) {
  __builtin_amdgcn_global_load_lds(
      (const __attribute__((address_space(1))) void*)g,
      (__attribute__((address_space(3))) void*)l, 16, 0, 0);
}

// ---------- fused LN over f32 [T,384] -> bf16 token-major ----------
__global__ __launch_bounds__(256) void ln_fused_f32_384(
    const float* __restrict__ in, const float* __restrict__ g,
    const float* __restrict__ b, unsigned short* __restrict__ out) {
  const int tok = blockIdx.x * 4 + (threadIdx.x >> 6);
  const int lane = threadIdx.x & 63;
  const float2* row = (const float2*)(in + (size_t)tok * 384);
  float2 v[3];
  float s = 0.f, ss = 0.f;
#pragma unroll
  for (int k = 0; k < 3; k++) {
    v[k] = row[lane + 64 * k];
    s += v[k].x + v[k].y;
    ss += v[k].x * v[k].x + v[k].y * v[k].y;
  }
#pragma unroll
  for (int off = 32; off > 0; off >>= 1) {
    s += __shfl_xor(s, off);
    ss += __shfl_xor(ss, off);
  }
  const float m = s * (1.0f / 384.0f);
  const float r = rsqrtf(ss * (1.0f / 384.0f) - m * m + 1e-5f);
  unsigned int* op = (unsigned int*)(out + (size_t)tok * 384);
#pragma unroll
  for (int k = 0; k < 3; k++) {
    const int c = lane + 64 * k;
    const float2 gg = ((const float2*)g)[c];
    const float2 bb = ((const float2*)b)[c];
    op[c] = pack2((v[k].x - m) * r * gg.x + bb.x, (v[k].y - m) * r * gg.y + bb.y);
  }
}

// ---------- LN over bundle bf16 [cg][b][pos][8ch] -> token-major ----------
__global__ __launch_bounds__(256) void ln_bundle_768(
    const uint4* __restrict__ mixed, const float* __restrict__ g,
    const float* __restrict__ b, uint4* __restrict__ out) {
  const int tid = threadIdx.x;
  const int tk = tid >> 2, j = tid & 3;
  const int token = blockIdx.x * 64 + tk;
  const int bb_ = token >> 12, posb = token & 4095;
  const size_t slab = (size_t)bb_ * 4096 + posb;
  float s = 0.f, ss = 0.f;
#pragma unroll 1
  for (int cg = j; cg < 96; cg += 4) {
    const uint4 v = mixed[((size_t)cg * 16) * 4096 + slab];
    float e0, e1, e2, e3, e4, e5, e6, e7;
    unpack2(v.x, e0, e1); unpack2(v.y, e2, e3);
    unpack2(v.z, e4, e5); unpack2(v.w, e6, e7);
    s += (e0 + e1) + (e2 + e3) + (e4 + e5) + (e6 + e7);
    ss += e0 * e0 + e1 * e1 + e2 * e2 + e3 * e3 + e4 * e4 + e5 * e5 +
          e6 * e6 + e7 * e7;
  }
  s += __shfl_xor(s, 1); ss += __shfl_xor(ss, 1);
  s += __shfl_xor(s, 2); ss += __shfl_xor(ss, 2);
  const float m = s * (1.0f / 768.0f);
  const float r = rsqrtf(ss * (1.0f / 768.0f) - m * m + 1e-5f);
  const size_t tokbase = (size_t)token * 96;
#pragma unroll 1
  for (int cg = j; cg < 96; cg += 4) {
    const uint4 v = mixed[((size_t)cg * 16) * 4096 + slab];
    const float4 g0 = *(const float4*)(g + cg * 8);
    const float4 g1 = *(const float4*)(g + cg * 8 + 4);
    const float4 b0 = *(const float4*)(b + cg * 8);
    const float4 b1 = *(const float4*)(b + cg * 8 + 4);
    float e0, e1, e2, e3, e4, e5, e6, e7;
    unpack2(v.x, e0, e1); unpack2(v.y, e2, e3);
    unpack2(v.z, e4, e5); unpack2(v.w, e6, e7);
    uint4 o;
    o.x = pack2((e0 - m) * r * g0.x + b0.x, (e1 - m) * r * g0.y + b0.y);
    o.y = pack2((e2 - m) * r * g0.z + b0.z, (e3 - m) * r * g0.w + b0.w);
    o.z = pack2((e4 - m) * r * g1.x + b1.x, (e5 - m) * r * g1.y + b1.y);
    o.w = pack2((e6 - m) * r * g1.z + b1.z, (e7 - m) * r * g1.w + b1.w);
    out[tokbase + cg] = o;
  }
}

// ---------- weight prep: f32 [K,N] -> bf16 [N,K] ----------
__global__ __launch_bounds__(256) void wprep_kernel(const float* __restrict__ in,
                                                    unsigned short* __restrict__ out,
                                                    int K, int N) {
  __shared__ float t[32][33];
  const int k0 = blockIdx.x * 32, n0 = blockIdx.y * 32;
  const int a = threadIdx.x & 31, b8 = threadIdx.x >> 5;
#pragma unroll
  for (int i = 0; i < 4; i++)
    t[b8 + 8 * i][a] = in[(size_t)(k0 + b8 + 8 * i) * N + n0 + a];
  __syncthreads();
#pragma unroll
  for (int i = 0; i < 4; i++)
    out[(size_t)(n0 + b8 + 8 * i) * K + k0 + a] = f2bf(t[a][b8 + 8 * i]);
}

// ---------- GEMM 2-phase dbuf; EPI: 1=f32+res, 2=gelu bf16, 3=bundle bf16 ---
template <int EPI>
__global__ __launch_bounds__(256) void gemm_bt_kernel(
    const unsigned short* __restrict__ A, int lda,
    const unsigned short* __restrict__ Bt, int ldb, int KT,
    const float* __restrict__ bias, const float* __restrict__ res,
    void* __restrict__ C, int ldc, int nby) {
  __shared__ unsigned short smem[32768];  // 64KB: As 2x16KB | Bs 2x16KB
  char* const smc = (char*)smem;

  const int tid = threadIdx.x;
  const int w = tid >> 6, lane = tid & 63;
  const int cpx = gridDim.x >> 3;
  const int g = blockIdx.x;
  const int sw = (g & 7) * cpx + (g >> 3);
  const int bx = sw / nby, by = sw - bx * nby;
  const int tok0 = bx << 7, n0 = by << 7;

  const int wm = w >> 1, wn = w & 1;
  const int lrow = lane & 15, kgrp = lane >> 4;
  const int cx = lrow & 7;

  const int lr8 = lane >> 3;
  const int kce = ((lane & 7) ^ lr8) << 3;
  const unsigned short* Abase = A + (size_t)(tok0 + w * 32 + lr8) * lda + kce;
  const unsigned short* Bbase = Bt + (size_t)(n0 + w * 32 + lr8) * ldb + kce;

  f32x4 acc[4][4];
#pragma unroll
  for (int i = 0; i < 4; i++)
#pragma unroll
    for (int j = 0; j < 4; j++) {
      f32x4 z = {0.f, 0.f, 0.f, 0.f};
      acc[i][j] = z;
    }

  const int nt = KT >> 6;
#pragma unroll
  for (int i = 0; i < 4; i++) {
    gload16(Abase + (size_t)i * 8 * lda, smc + (w * 4 + i) * 1024);
    gload16(Bbase + (size_t)i * 8 * ldb, smc + 32768 + (w * 4 + i) * 1024);
  }
  __syncthreads();

  int buf = 0;
  for (int t = 0; t < nt; t++) {
    if (t + 1 < nt) {
      const int kt = (t + 1) << 6;
      const int bo = (buf ^ 1) * 16384;
#pragma unroll
      for (int i = 0; i < 4; i++) {
        gload16(Abase + (size_t)i * 8 * lda + kt, smc + bo + (w * 4 + i) * 1024);
        gload16(Bbase + (size_t)i * 8 * ldb + kt,
                smc + 32768 + bo + (w * 4 + i) * 1024);
      }
    }
    bf16x8 af[2][4], bf_[2][4];
    const int bo = buf * 16384;
#pragma unroll
    for (int ks = 0; ks < 2; ks++) {
#pragma unroll
      for (int f = 0; f < 4; f++) {
        const int co = ((ks * 4 + kgrp) ^ cx) << 4;
        af[ks][f] =
            *(const bf16x8*)(smc + bo + (wm * 64 + f * 16 + lrow) * 128 + co);
        bf_[ks][f] = *(const bf16x8*)(smc + 32768 + bo +
                                      (wn * 64 + f * 16 + lrow) * 128 + co);
      }
    }
#pragma unroll
    for (int ks = 0; ks < 2; ks++)
#pragma unroll
      for (int mf = 0; mf < 4; mf++)
#pragma unroll
        for (int nf = 0; nf < 4; nf++)
          acc[mf][nf] = __builtin_amdgcn_mfma_f32_16x16x32_bf16(
              af[ks][mf], bf_[ks][nf], acc[mf][nf], 0, 0, 0);
    __syncthreads();
    buf ^= 1;
  }

  if constexpr (EPI == 3) {
#pragma unroll
    for (int mf = 0; mf < 4; mf++)
#pragma unroll
      for (int nf = 0; nf < 4; nf++) {
        const int cl = wn * 64 + nf * 16 + lrow;
        const float bv = bias[n0 + cl];
#pragma unroll
        for (int r = 0; r < 4; r++) {
          const int tl = wm * 64 + mf * 16 + kgrp * 4 + r;
          smem[(cl >> 3) * 1032 + tl * 8 + (cl & 7)] =
              f2bf(acc[mf][nf][r] + bv);
        }
      }
    __syncthreads();
    const int bb_ = tok0 >> 12, pos0 = tok0 & 4095, cg0 = n0 >> 3;
    uint4* Cb = (uint4*)C;
#pragma unroll
    for (int e = 0; e < 8; e++) {
      const int lin = e * 256 + tid;
      const int cgl = lin >> 7, pp = lin & 127;
      const uint4 v = *(const uint4*)&smem[cgl * 1032 + pp * 8];
      Cb[((size_t)(cg0 + cgl) * 16 + bb_) * 4096 + pos0 + pp] = v;
    }
  } else {
#pragma unroll
    for (int mf = 0; mf < 4; mf++) {
#pragma unroll
      for (int nf = 0; nf < 4; nf++) {
        const int gcol = n0 + wn * 64 + nf * 16 + lrow;
        const float bv = bias ? bias[gcol] : 0.0f;
#pragma unroll
        for (int r = 0; r < 4; r++) {
          const int grow = tok0 + wm * 64 + mf * 16 + kgrp * 4 + r;
          float v = acc[mf][nf][r] + bv;
          const size_t idx = (size_t)grow * ldc + gcol;
          if constexpr (EPI == 1) {
            ((float*)C)[idx] = v + res[idx];
          } else {
            const float z = 1.5957691216057308f * (v + 0.044715f * v * v * v);
            const float gl = v / (1.0f + __expf(-z));
            ((unsigned short*)C)[idx] = f2bf(gl);
          }
        }
      }
    }
  }
}

// ---------- segmented bidirectional EMA over a register-held segment -------
__device__ __forceinline__ void ema_seg_reg(const unsigned int vals[16],
                                            const int seg,
                                            unsigned int res[16]) {
  const float A16 = 2.8211099e-4f;   // 0.6^16
  const float A32 = 7.9586611e-8f;   // 0.6^32
  float a, bv, t;
  float za = 0.f, zb = 0.f;
#pragma unroll
  for (int j = 0; j < 16; j++) {
    unpack2(vals[j], a, bv);
    za = 0.6f * za + 0.4f * a;
    zb = 0.6f * zb + 0.4f * bv;
  }
  t = __shfl_up(za, 1); if (seg >= 1) za += A16 * t;
  t = __shfl_up(zb, 1); if (seg >= 1) zb += A16 * t;
  t = __shfl_up(za, 2); if (seg >= 2) za += A32 * t;
  t = __shfl_up(zb, 2); if (seg >= 2) zb += A32 * t;
  float yfa = __shfl_up(za, 1), yfb = __shfl_up(zb, 1);
  if (seg == 0) { yfa = 0.f; yfb = 0.f; }
  float ua = 0.f, ub = 0.f;
#pragma unroll
  for (int j = 15; j >= 0; j--) {
    unpack2(vals[j], a, bv);
    ua = 0.6f * ua + 0.4f * a;
    ub = 0.6f * ub + 0.4f * bv;
  }
  t = __shfl_down(ua, 1); if (seg <= 2) ua += A16 * t;
  t = __shfl_down(ub, 1); if (seg <= 2) ub += A16 * t;
  t = __shfl_down(ua, 2); if (seg <= 1) ua += A32 * t;
  t = __shfl_down(ub, 2); if (seg <= 1) ub += A32 * t;
  float zba = __shfl_down(ua, 1), zbb = __shfl_down(ub, 1);
  if (seg == 3) { zba = 0.f; zbb = 0.f; }
  float fa = yfa, fb = yfb;
#pragma unroll
  for (int j = 0; j < 16; j++) {
    unpack2(vals[j], a, bv);
    fa = 0.6f * fa + 0.4f * a;
    fb = 0.6f * fb + 0.4f * bv;
    res[j] = pack2(fa, fb);
  }
  float ga = zba, gb = zbb;
#pragma unroll
  for (int j = 15; j >= 0; j--) {
    unpack2(vals[j], a, bv);
    ga = 0.6f * ga + 0.4f * a;
    gb = 0.6f * gb + 0.4f * bv;
    float ffa, ffb;
    unpack2(res[j], ffa, ffb);
    res[j] = pack2(0.25f * (ffa + ga), 0.25f * (ffb + gb));
  }
}

// ---------- fused dwconv3x3 + 4 EMA scans on bundle layout ----------
// 512 threads (R8-proven 128-VGPR cap). Thread = (cp01, line, seg); owns
// planes cpA = cp01 and cpB = cp01+2. Segmented scans, ~90 live VGPR.
__global__ __launch_bounds__(512) void conv_scan_kernel(
    const uint4* __restrict__ p, const float* __restrict__ kconv,
    uint4* __restrict__ mixed) {
  __shared__ unsigned int loc[4][64][65];  // 66.56 KB
  __shared__ float klds[72];
  const int tid = threadIdx.x;
  const int cg = blockIdx.x;  // 0..95
  const int b = blockIdx.y;   // 0..15
  const uint4* pb = p + ((size_t)cg * 16 + b) * 4096;

  if (tid < 72) klds[tid] = kconv[(tid >> 3) * DINNER + cg * 8 + (tid & 7)];
  __syncthreads();

#pragma unroll 1
  for (int i = 0; i < 8; i++) {
    const int pos = tid + 512 * i;
    const int h = pos >> 6, w = pos & 63;
    float acc[8];
#pragma unroll
    for (int j = 0; j < 8; j++) acc[j] = 0.f;
#pragma unroll
    for (int dh = 0; dh < 3; dh++) {
      const int hh = h + dh - 1;
      const bool vh = (unsigned)hh < 64u;
      const int hcl = min(max(hh, 0), 63);
#pragma unroll
      for (int dw = 0; dw < 3; dw++) {
        const int ww = w + dw - 1;
        const bool vv = vh && ((unsigned)ww < 64u);
        const int wcl = min(max(ww, 0), 63);
        uint4 pv = pb[hcl * 64 + wcl];
        if (!vv) { pv.x = 0; pv.y = 0; pv.z = 0; pv.w = 0; }
        const int t = dh * 3 + dw;
        float lo, hi;
        unpack2(pv.x, lo, hi);
        acc[0] += lo * klds[t * 8 + 0]; acc[1] += hi * klds[t * 8 + 1];
        unpack2(pv.y, lo, hi);
        acc[2] += lo * klds[t * 8 + 2]; acc[3] += hi * klds[t * 8 + 3];
        unpack2(pv.z, lo, hi);
        acc[4] += lo * klds[t * 8 + 4]; acc[5] += hi * klds[t * 8 + 5];
        unpack2(pv.w, lo, hi);
        acc[6] += lo * klds[t * 8 + 6]; acc[7] += hi * klds[t * 8 + 7];
      }
    }
    loc[0][h][w] = pack2(acc[0], acc[1]);
    loc[1][h][w] = pack2(acc[2], acc[3]);
    loc[2][h][w] = pack2(acc[4], acc[5]);
    loc[3][h][w] = pack2(acc[6], acc[7]);
  }
  __syncthreads();

  const int seg = tid & 3;          // segment within line
  const int ax = (tid >> 2) & 63;   // line index (col for H, row for W)
  const int cpA = tid >> 8;         // 0 or 1
  const int cpB = cpA + 2;
  const int j0 = seg * 16;

  // H phase: columns (read-only); contributions held in regs for 2 planes
  unsigned int hconA[16], hconB[16];
  {
    unsigned int vals[16];
#pragma unroll
    for (int j = 0; j < 16; j++) vals[j] = loc[cpA][j0 + j][ax];
    ema_seg_reg(vals, seg, hconA);
#pragma unroll
    for (int j = 0; j < 16; j++) vals[j] = loc[cpB][j0 + j][ax];
    ema_seg_reg(vals, seg, hconB);
  }
  __syncthreads();

  // W phase: rows; own-segment read + write (out = v + 0.25*(lr+rl))
  {
    unsigned int vals[16], wcon[16];
#pragma unroll
    for (int j = 0; j < 16; j++) vals[j] = loc[cpA][ax][j0 + j];
    ema_seg_reg(vals, seg, wcon);
#pragma unroll
    for (int j = 0; j < 16; j++) {
      float a, bv, ra, rb;
      unpack2(vals[j], a, bv);
      unpack2(wcon[j], ra, rb);
      loc[cpA][ax][j0 + j] = pack2(a + ra, bv + rb);
    }
#pragma unroll
    for (int j = 0; j < 16; j++) vals[j] = loc[cpB][ax][j0 + j];
    ema_seg_reg(vals, seg, wcon);
#pragma unroll
    for (int j = 0; j < 16; j++) {
      float a, bv, ra, rb;
      unpack2(vals[j], a, bv);
      unpack2(wcon[j], ra, rb);
      loc[cpB][ax][j0 + j] = pack2(a + ra, bv + rb);
    }
  }
  __syncthreads();

  // ADD phase: += 0.25*(tb+bt) down own column-segments
#pragma unroll
  for (int j = 0; j < 16; j++) {
    float a, bv, ra, rb;
    unpack2(loc[cpA][j0 + j][ax], a, bv);
    unpack2(hconA[j], ra, rb);
    loc[cpA][j0 + j][ax] = pack2(a + ra, bv + rb);
  }
#pragma unroll
  for (int j = 0; j < 16; j++) {
    float a, bv, ra, rb;
    unpack2(loc[cpB][j0 + j][ax], a, bv);
    unpack2(hconB[j], ra, rb);
    loc[cpB][j0 + j][ax] = pack2(a + ra, bv + rb);
  }
  __syncthreads();

  uint4* mb = mixed + ((size_t)cg * 16 + b) * 4096;
#pragma unroll 1
  for (int i = 0; i < 8; i++) {
    const int pos = tid + 512 * i;
    const int h = pos >> 6, w = pos & 63;
    uint4 st;
    st.x = loc[0][h][w];
    st.y = loc[1][h][w];
    st.z = loc[2][h][w];
    st.w = loc[3][h][w];
    mb[pos] = st;
  }
}

extern "C" void kernel_launch(void* const* d_in, const int* in_sizes, int n_in,
                              void* d_out, int out_size, void* d_ws,
                              size_t ws_size, hipStream_t stream) {
  const float* x = (const float*)d_in[0];
  const float* n1_g = (const float*)d_in[1];
  const float* n1_b = (const float*)d_in[2];
  const float* w_in = (const float*)d_in[3];
  const float* b_in = (const float*)d_in[4];
  const float* k_conv = (const float*)d_in[5];
  const float* on_g = (const float*)d_in[6];
  const float* on_b = (const float*)d_in[7];
  const float* w_out = (const float*)d_in[8];
  const float* b_out = (const float*)d_in[9];
  const float* n2_g = (const float*)d_in[10];
  const float* n2_b = (const float*)d_in[11];
  const float* w1 = (const float*)d_in[12];
  const float* b1 = (const float*)d_in[13];
  const float* w2 = (const float*)d_in[14];
  const float* b2 = (const float*)d_in[15];

  const size_t MB = 1024 * 1024;
  char* ws = (char*)d_ws;
  unsigned short* R1 = (unsigned short*)(ws + 3 * MB / 2);
  unsigned short* R2 = (unsigned short*)(ws + 3 * MB / 2 + 96 * MB);

  unsigned short* A1 = R2;                         // 48MB token-major
  unsigned short* wTin = R2 + (48 * MB) / 2;       // [768][384]
  unsigned short* p = R1;                          // 96MB BUNDLE; in-place
  unsigned short* A2 = R2;                         // 96MB token-major
  unsigned short* wTout = R1;                      // [384][768] (p dead)
  unsigned short* A3 = R1;                         // 48MB
  unsigned short* wT1 = R1 + (48 * MB) / 2;        // [1536][384]
  unsigned short* wT2 = wT1 + (size_t)1536 * 384;  // [384][1536]
  unsigned short* gb = R2;                         // 96MB token-major

  float* out = (float*)d_out;
  dim3 b256(256);

  // LN1(x) -> A1
  ln_fused_f32_384<<<T_TOKENS / 4, b256, 0, stream>>>(x, n1_g, n1_b, A1);
  wprep_kernel<<<dim3(12, 24), b256, 0, stream>>>(w_in, wTin, DMODEL, DINNER);
  // p(bundle) = A1 @ w_in + b_in
  gemm_bt_kernel<3><<<3072, b256, 0, stream>>>(A1, DMODEL, wTin, DMODEL, DMODEL,
                                               b_in, nullptr, p, DINNER, 6);
  // mixed(bundle) = conv+scan(p), in place
  conv_scan_kernel<<<dim3(96, 16), dim3(512), 0, stream>>>(
      (const uint4*)p, k_conv, (uint4*)p);
  // LN(on)(mixed bundle) -> A2 token-major
  ln_bundle_768<<<1024, b256, 0, stream>>>((const uint4*)p, on_g, on_b,
                                           (uint4*)A2);
  wprep_kernel<<<dim3(24, 12), b256, 0, stream>>>(w_out, wTout, DINNER, DMODEL);
  // out = x + A2 @ w_out + b_out
  gemm_bt_kernel<1><<<1536, b256, 0, stream>>>(A2, DINNER, wTout, DINNER, DINNER,
                                               b_out, x, out, DMODEL, 3);
  // LN2(out) -> A3
  ln_fused_f32_384<<<T_TOKENS / 4, b256, 0, stream>>>(out, n2_g, n2_b, A3);
  wprep_kernel<<<dim3(12, 48), b256, 0, stream>>>(w1, wT1, DMODEL, DHIDDEN);
  wprep_kernel<<<dim3(48, 12), b256, 0, stream>>>(w2, wT2, DHIDDEN, DMODEL);
  // MLP split by tokens
  for (int hh = 0; hh < 2; hh++) {
    const size_t toff = (size_t)hh * 32768;
    gemm_bt_kernel<2><<<3072, b256, 0, stream>>>(
        A3 + toff * DMODEL, DMODEL, wT1, DMODEL, DMODEL, b1, nullptr, gb,
        DHIDDEN, 12);
    gemm_bt_kernel<1><<<768, b256, 0, stream>>>(
        gb, DHIDDEN, wT2, DHIDDEN, DHIDDEN, b2, out + toff * DMODEL,
        out + toff * DMODEL, DMODEL, 3);
  }
}